// Round 1
// baseline (66688.159 us; speedup 1.0000x reference)
//
#include <hip/hip_runtime.h>
#include <hip/hip_bf16.h>

#define BB 64
#define TT 2048
#define HH 256
#define H4 1024
#define NC 10
#define NWG 128

struct Bar { unsigned count; unsigned phase; };

__device__ __forceinline__ float sigmoidf_(float x) {
    return 1.0f / (1.0f + expf(-x));
}

// ---------------------------------------------------------------------------
// gx GEMM: gx[tc][n][b] = sum_k A[b][t0+tc][k] * W[n][k] + bias1[n] + bias2[n]
// M = TC*64 (m = tc*64 + b), N = 1024, K = 256. 128x128 tiles, 8x8/thread.
// ---------------------------------------------------------------------------
__global__ __launch_bounds__(256, 2)
void gemm_gx(const float* __restrict__ A, const float* __restrict__ W,
             const float* __restrict__ bias1, const float* __restrict__ bias2,
             float* __restrict__ gx, int t0)
{
    __shared__ float As[8][132];
    __shared__ float Bs[8][132];
    const int tid = threadIdx.x;
    const int m0 = blockIdx.y * 128, n0 = blockIdx.x * 128;
    const int tx = tid & 15, ty = tid >> 4;

    float acc[8][8];
#pragma unroll
    for (int i = 0; i < 8; i++)
#pragma unroll
        for (int j = 0; j < 8; j++) acc[i][j] = 0.f;

    const int mL = tid >> 1, half = tid & 1;
    const int gm = m0 + mL;
    const int b = gm & 63, tc = gm >> 6;
    const float* arow = A + ((size_t)b * TT + t0 + tc) * 256;
    const float* brow = W + (size_t)(n0 + mL) * 256;

    for (int k0 = 0; k0 < 256; k0 += 8) {
        float4 av = *(const float4*)(arow + k0 + half * 4);
        float4 bv = *(const float4*)(brow + k0 + half * 4);
        __syncthreads();
        As[half * 4 + 0][mL] = av.x; As[half * 4 + 1][mL] = av.y;
        As[half * 4 + 2][mL] = av.z; As[half * 4 + 3][mL] = av.w;
        Bs[half * 4 + 0][mL] = bv.x; Bs[half * 4 + 1][mL] = bv.y;
        Bs[half * 4 + 2][mL] = bv.z; Bs[half * 4 + 3][mL] = bv.w;
        __syncthreads();
#pragma unroll
        for (int k = 0; k < 8; k++) {
            float a[8], w[8];
            *(float4*)&a[0] = *(const float4*)&As[k][ty * 8];
            *(float4*)&a[4] = *(const float4*)&As[k][ty * 8 + 4];
            *(float4*)&w[0] = *(const float4*)&Bs[k][tx * 8];
            *(float4*)&w[4] = *(const float4*)&Bs[k][tx * 8 + 4];
#pragma unroll
            for (int i = 0; i < 8; i++)
#pragma unroll
                for (int j = 0; j < 8; j++) acc[i][j] += a[i] * w[j];
        }
    }
#pragma unroll
    for (int i = 0; i < 8; i++) {
        int m = m0 + ty * 8 + i;
        int bb = m & 63, tcc = m >> 6;
#pragma unroll
        for (int j = 0; j < 8; j++) {
            int n = n0 + tx * 8 + j;
            gx[((size_t)tcc * H4 + n) * 64 + bb] = acc[i][j] + bias1[n] + bias2[n];
        }
    }
}

// ---------------------------------------------------------------------------
// Persistent recurrent LSTM kernel. 128 WGs x 256 threads, each WG owns 2
// hidden units (8 rows of W_hh). Custom device-wide barrier per timestep.
// gx layout: [tc][n(1024)][b(64)]. hbuf double-buffered: h_t -> hbuf[t&1].
// ---------------------------------------------------------------------------
__global__ __launch_bounds__(256, 1)
void lstm_rec(const float* __restrict__ gx, const float* __restrict__ Whh,
              float* __restrict__ hbuf, float* __restrict__ cbuf,
              float* __restrict__ h1out, Bar* __restrict__ bar,
              int t0, int TC, int writeH1)
{
    __shared__ float Wl[8][264];
    __shared__ float hl[64][260];
    const int tid = threadIdx.x;
    const int wg = blockIdx.x;
    const unsigned nwg = gridDim.x;
    const int u0 = wg * 2;
    const int r = tid & 7, duo = tid >> 3;
    const int b0 = duo * 2, b1v = duo * 2 + 1;
    const int ul = r & 1;
    const int grow_t = (r >> 1) * HH + u0 + ul;   // this thread's global gate row

    // load W_hh slice (8 rows) into LDS, once
#pragma unroll
    for (int rep = 0; rep < 2; rep++) {
        int idx = rep * 256 + tid;
        int row = idx >> 6, q = idx & 63;
        int gr = (row >> 1) * HH + u0 + (row & 1);
        float4 v = *(const float4*)(Whh + (size_t)gr * 256 + q * 4);
        *(float4*)&Wl[row][q * 4] = v;
    }

    float c0 = 0.f, c1 = 0.f;
    if (r < 2) {
        c0 = cbuf[b0 * HH + u0 + r];
        c1 = cbuf[b1v * HH + u0 + r];
    }

    unsigned lphase = 0;
    const int lane = tid & 63;
    const int sbase = ((lane >> 3) << 3) + ul;

    for (int t = t0; t < t0 + TC; t++) {
        const int tc = t - t0;
        // prefetch this step's gx values early (hide HBM latency under the dot)
        float gxa = gx[((size_t)tc * H4 + grow_t) * 64 + b0];
        float gxb = gx[((size_t)tc * H4 + grow_t) * 64 + b1v];

        // stage h_{t-1} (hbuf[(t-1)&1] == hbuf[(t+1)&1]) into LDS
        const float* hp = hbuf + ((t + 1) & 1) * (BB * HH);
#pragma unroll
        for (int rep = 0; rep < 16; rep++) {
            int idx = rep * 256 + tid;
            int bb = idx >> 6, q = idx & 63;
            float4 v = *(const float4*)(hp + bb * 256 + q * 4);
            *(float4*)&hl[bb][q * 4] = v;
        }
        __syncthreads();

        float acc0 = 0.f, acc1 = 0.f;
#pragma unroll 8
        for (int k = 0; k < 256; k += 4) {
            float4 w  = *(const float4*)&Wl[r][k];
            float4 x0 = *(const float4*)&hl[b0][k];
            float4 x1 = *(const float4*)&hl[b1v][k];
            acc0 += w.x * x0.x + w.y * x0.y + w.z * x0.z + w.w * x0.w;
            acc1 += w.x * x1.x + w.y * x1.y + w.z * x1.z + w.w * x1.w;
        }
        float pre0 = acc0 + gxa;
        float pre1 = acc1 + gxb;

        // gather 4 gates for (unit ul, batch b) from lanes of same duo
        float i0 = __shfl(pre0, sbase + 0, 64);
        float f0 = __shfl(pre0, sbase + 2, 64);
        float g0 = __shfl(pre0, sbase + 4, 64);
        float o0 = __shfl(pre0, sbase + 6, 64);
        float i1 = __shfl(pre1, sbase + 0, 64);
        float f1 = __shfl(pre1, sbase + 2, 64);
        float g1 = __shfl(pre1, sbase + 4, 64);
        float o1 = __shfl(pre1, sbase + 6, 64);

        if (r < 2) {
            float ia = sigmoidf_(i0), fa = sigmoidf_(f0);
            float ga = tanhf(g0),     oa = sigmoidf_(o0);
            c0 = fa * c0 + ia * ga;
            float h0 = oa * tanhf(c0);
            float ib = sigmoidf_(i1), fb = sigmoidf_(f1);
            float gb = tanhf(g1),     ob = sigmoidf_(o1);
            c1 = fb * c1 + ib * gb;
            float h1 = ob * tanhf(c1);
            float* hc = hbuf + (t & 1) * (BB * HH);
            hc[b0 * HH + u0 + r]  = h0;
            hc[b1v * HH + u0 + r] = h1;
            if (writeH1) {
                h1out[((size_t)b0 * TT + t) * HH + u0 + r]  = h0;
                h1out[((size_t)b1v * TT + t) * HH + u0 + r] = h1;
            }
        }

        // device-wide barrier (monotonic counter, release/acquire via fences)
        __syncthreads();
        if (tid == 0) {
            __threadfence();
            unsigned target = ++lphase;
            unsigned old = atomicAdd(&bar->count, 1u);
            if (old == nwg * target - 1u) {
                __hip_atomic_store(&bar->phase, target, __ATOMIC_RELEASE,
                                   __HIP_MEMORY_SCOPE_AGENT);
            } else {
                while (__hip_atomic_load(&bar->phase, __ATOMIC_ACQUIRE,
                                         __HIP_MEMORY_SCOPE_AGENT) < target) {}
            }
            __threadfence();
        } else {
            lphase++;
        }
        __syncthreads();
    }

    if (r < 2) {
        cbuf[b0 * HH + u0 + r]  = c0;
        cbuf[b1v * HH + u0 + r] = c1;
    }
}

// ---------------------------------------------------------------------------
__global__ void fc_kernel(const float* __restrict__ h2,
                          const float* __restrict__ Wfc,
                          const float* __restrict__ bfc,
                          float* __restrict__ out)
{
    __shared__ float hs[256];
    int b = blockIdx.x, tid = threadIdx.x;
    hs[tid] = h2[b * HH + tid];
    __syncthreads();
    if (tid < NC) {
        float s = bfc[tid];
        for (int k = 0; k < 256; k++) s += hs[k] * Wfc[tid * 256 + k];
        out[b * NC + tid] = s;
    }
}

// ---------------------------------------------------------------------------
extern "C" void kernel_launch(void* const* d_in, const int* in_sizes, int n_in,
                              void* d_out, int out_size, void* d_ws, size_t ws_size,
                              hipStream_t stream)
{
    const float* x    = (const float*)d_in[0];
    const float* Wih0 = (const float*)d_in[1];
    const float* Whh0 = (const float*)d_in[2];
    const float* bih0 = (const float*)d_in[3];
    const float* bhh0 = (const float*)d_in[4];
    const float* Wih1 = (const float*)d_in[5];
    const float* Whh1 = (const float*)d_in[6];
    const float* bih1 = (const float*)d_in[7];
    const float* bhh1 = (const float*)d_in[8];
    const float* Wfc  = (const float*)d_in[9];
    const float* bfc  = (const float*)d_in[10];

    float* ws = (float*)d_ws;
    const size_t h1_elems = (size_t)BB * TT * HH;      // 33.5M floats (128 MB)

    int TC = 2048;
    while (TC > 32) {
        size_t need = (h1_elems + (size_t)TC * 64 * H4 + 3 * BB * HH + 256) * 4;
        if (need <= ws_size) break;
        TC >>= 1;
    }

    float* h1 = ws;
    float* gxb = ws + h1_elems;
    float* hb  = gxb + (size_t)TC * 64 * H4;
    float* cb  = hb + 2 * BB * HH;
    Bar*   bar = (Bar*)(cb + BB * HH + 64);

    const int nchunk = TT / TC;

    for (int layer = 0; layer < 2; layer++) {
        const float* A    = layer ? h1   : x;
        const float* Wih  = layer ? Wih1 : Wih0;
        const float* Whh  = layer ? Whh1 : Whh0;
        const float* bih  = layer ? bih1 : bih0;
        const float* bhh  = layer ? bhh1 : bhh0;

        hipMemsetAsync(hb, 0, (size_t)2 * BB * HH * 4, stream);
        hipMemsetAsync(cb, 0, (size_t)BB * HH * 4, stream);

        for (int ch = 0; ch < nchunk; ch++) {
            int t0 = ch * TC;
            dim3 gg(8, TC * 64 / 128);
            gemm_gx<<<gg, 256, 0, stream>>>(A, Wih, bih, bhh, gxb, t0);
            hipMemsetAsync(bar, 0, sizeof(Bar), stream);
            lstm_rec<<<NWG, 256, 0, stream>>>(gxb, Whh, hb, cb,
                                              layer == 0 ? h1 : nullptr, bar,
                                              t0, TC, layer == 0 ? 1 : 0);
        }
    }

    fc_kernel<<<BB, 256, 0, stream>>>(hb + BB * HH, Wfc, bfc, (float*)d_out);
}

// Round 2
// 51462.305 us; speedup vs baseline: 1.2959x; 1.2959x over previous
//
#include <hip/hip_runtime.h>
#include <hip/hip_bf16.h>

#define BB 64
#define TT 2048
#define HH 256
#define H4 1024
#define NC 10
#define NWG1 128          // layer-1 WGs
#define NWGT 256          // total WGs (128 layer-1 + 128 layer-2)
#define BBHH (BB * HH)

struct __align__(128) Bar {
    unsigned count; unsigned pad0[31];   // own cacheline
    unsigned phase; unsigned pad1[31];   // own cacheline
};

__device__ __forceinline__ float sigmoidf_(float x) {
    return 1.0f / (1.0f + expf(-x));
}

// ---------------------------------------------------------------------------
// gx GEMM (layer 1 input contribution only):
// gx[tc][n][b] = sum_k x[b][t0+tc][k] * W[n][k] + bih[n] + bhh[n]
// M = TC*64 (m = tc*64 + b), N = 1024, K = 256. 128x128 tiles, 8x8/thread.
// ---------------------------------------------------------------------------
__global__ __launch_bounds__(256, 2)
void gemm_gx(const float* __restrict__ A, const float* __restrict__ W,
             const float* __restrict__ bias1, const float* __restrict__ bias2,
             float* __restrict__ gx, int t0)
{
    __shared__ float As[8][132];
    __shared__ float Bs[8][132];
    const int tid = threadIdx.x;
    const int m0 = blockIdx.y * 128, n0 = blockIdx.x * 128;
    const int tx = tid & 15, ty = tid >> 4;

    float acc[8][8];
#pragma unroll
    for (int i = 0; i < 8; i++)
#pragma unroll
        for (int j = 0; j < 8; j++) acc[i][j] = 0.f;

    const int mL = tid >> 1, half = tid & 1;
    const int gm = m0 + mL;
    const int b = gm & 63, tc = gm >> 6;
    const float* arow = A + ((size_t)b * TT + t0 + tc) * 256;
    const float* brow = W + (size_t)(n0 + mL) * 256;

    for (int k0 = 0; k0 < 256; k0 += 8) {
        float4 av = *(const float4*)(arow + k0 + half * 4);
        float4 bv = *(const float4*)(brow + k0 + half * 4);
        __syncthreads();
        As[half * 4 + 0][mL] = av.x; As[half * 4 + 1][mL] = av.y;
        As[half * 4 + 2][mL] = av.z; As[half * 4 + 3][mL] = av.w;
        Bs[half * 4 + 0][mL] = bv.x; Bs[half * 4 + 1][mL] = bv.y;
        Bs[half * 4 + 2][mL] = bv.z; Bs[half * 4 + 3][mL] = bv.w;
        __syncthreads();
#pragma unroll
        for (int k = 0; k < 8; k++) {
            float a[8], w[8];
            *(float4*)&a[0] = *(const float4*)&As[k][ty * 8];
            *(float4*)&a[4] = *(const float4*)&As[k][ty * 8 + 4];
            *(float4*)&w[0] = *(const float4*)&Bs[k][tx * 8];
            *(float4*)&w[4] = *(const float4*)&Bs[k][tx * 8 + 4];
#pragma unroll
            for (int i = 0; i < 8; i++)
#pragma unroll
                for (int j = 0; j < 8; j++) acc[i][j] += a[i] * w[j];
        }
    }
#pragma unroll
    for (int i = 0; i < 8; i++) {
        int m = m0 + ty * 8 + i;
        int bb = m & 63, tcc = m >> 6;
#pragma unroll
        for (int j = 0; j < 8; j++) {
            int n = n0 + tx * 8 + j;
            gx[((size_t)tcc * H4 + n) * 64 + bb] = acc[i][j] + bias1[n] + bias2[n];
        }
    }
}

// ---------------------------------------------------------------------------
// Merged persistent kernel: 256 WGs. WGs [0,128) = layer 1, [128,256) = layer 2
// (pipelined one step behind). Iteration i: layer-1 computes h1_i, layer-2
// computes h2_{i-1} from h1_{i-1} and h2_{i-2}. Rings of 2 in global ws.
// Only the final h2 is needed downstream (FC) -> no sequence materialization.
// ---------------------------------------------------------------------------
__global__ __launch_bounds__(256, 1)
void lstm_rec2(const float* __restrict__ gx, const float* __restrict__ Whh0,
               const float* __restrict__ Wih1, const float* __restrict__ Whh1,
               const float* __restrict__ bih1, const float* __restrict__ bhh1,
               float* __restrict__ h1r, float* __restrict__ h2r,
               float* __restrict__ c1b, float* __restrict__ c2b,
               Bar* __restrict__ bar, int t0, int l1cnt, int niter)
{
    __shared__ float Wl[2][8][264];   // [0]=Whh0 (L1) or Wih1 (L2); [1]=Whh1 (L2)
    __shared__ float hA[64][260];     // h1_{i-1} stage (both layers)
    __shared__ float hB[64][260];     // h2_{i-2} stage (layer 2 only)

    const int tid = threadIdx.x;
    const int wg = blockIdx.x;
    const bool isL2 = wg >= NWG1;
    const int u0 = (isL2 ? wg - NWG1 : wg) * 2;
    const int r = tid & 7, duo = tid >> 3;
    const int b0 = 2 * duo, b1 = 2 * duo + 1;
    const int ul = r & 1;
    const int grow = (r >> 1) * HH + u0 + ul;

    // stage this WG's 8 weight rows into LDS (once)
    {
        const float* W0 = isL2 ? Wih1 : Whh0;
#pragma unroll
        for (int rep = 0; rep < 2; rep++) {
            int idx = rep * 256 + tid;
            int row = idx >> 6, q = idx & 63;
            int gr = (row >> 1) * HH + u0 + (row & 1);
            *(float4*)&Wl[0][row][q * 4] = *(const float4*)(W0 + (size_t)gr * 256 + q * 4);
            if (isL2)
                *(float4*)&Wl[1][row][q * 4] = *(const float4*)(Whh1 + (size_t)gr * 256 + q * 4);
        }
    }
    float bs = 0.f;
    if (isL2) bs = bih1[grow] + bhh1[grow];

    float* cbuf = isL2 ? c2b : c1b;
    float c0 = 0.f, c1 = 0.f;
    if (r < 2) {
        c0 = cbuf[b0 * HH + u0 + r];
        c1 = cbuf[b1 * HH + u0 + r];
    }

    const int lane = tid & 63;
    const int sbase = ((lane >> 3) << 3) + ul;
    unsigned phase = 0;

    for (int j = 0; j < niter; j++) {
        const int i = t0 + j;
        const bool actL1 = (!isL2) && (j < l1cnt);
        const bool actL2 = isL2 && (i >= 1);

        // prefetch gx for this step early (HBM stream, independent of barrier)
        float gxa = 0.f, gxb_ = 0.f;
        if (actL1) {
            gxa  = gx[((size_t)j * H4 + grow) * BB + b0];
            gxb_ = gx[((size_t)j * H4 + grow) * BB + b1];
        }

        // stage hA = h1_{i-1} (slot (i+1)&1); L2 also stages hB = h2_{i-2} (slot i&1)
        const float* srcA = h1r + (size_t)((i + 1) & 1) * BBHH;
        const float* srcB = h2r + (size_t)(i & 1) * BBHH;
#pragma unroll
        for (int rep = 0; rep < 16; rep++) {
            int idx = rep * 256 + tid;
            int bb = idx >> 6, q = idx & 63;
            float4 vA = *(const float4*)(srcA + bb * HH + q * 4);
            *(float4*)&hA[bb][q * 4] = vA;
            if (isL2) {
                float4 vB = *(const float4*)(srcB + bb * HH + q * 4);
                *(float4*)&hB[bb][q * 4] = vB;
            }
        }
        __syncthreads();

        float pre0 = 0.f, pre1 = 0.f;
        if (actL1) {
            float a0 = 0.f, a1 = 0.f;
#pragma unroll 8
            for (int k = 0; k < 256; k += 4) {
                float4 w  = *(const float4*)&Wl[0][r][k];
                float4 x0 = *(const float4*)&hA[b0][k];
                float4 x1 = *(const float4*)&hA[b1][k];
                a0 += w.x * x0.x + w.y * x0.y + w.z * x0.z + w.w * x0.w;
                a1 += w.x * x1.x + w.y * x1.y + w.z * x1.z + w.w * x1.w;
            }
            pre0 = a0 + gxa;
            pre1 = a1 + gxb_;
        } else if (actL2) {
            float a0 = 0.f, a1 = 0.f;
#pragma unroll 4
            for (int k = 0; k < 256; k += 4) {
                float4 wI  = *(const float4*)&Wl[0][r][k];
                float4 wH  = *(const float4*)&Wl[1][r][k];
                float4 xA0 = *(const float4*)&hA[b0][k];
                float4 xA1 = *(const float4*)&hA[b1][k];
                float4 xB0 = *(const float4*)&hB[b0][k];
                float4 xB1 = *(const float4*)&hB[b1][k];
                a0 += wI.x * xA0.x + wI.y * xA0.y + wI.z * xA0.z + wI.w * xA0.w
                    + wH.x * xB0.x + wH.y * xB0.y + wH.z * xB0.z + wH.w * xB0.w;
                a1 += wI.x * xA1.x + wI.y * xA1.y + wI.z * xA1.z + wI.w * xA1.w
                    + wH.x * xB1.x + wH.y * xB1.y + wH.z * xB1.z + wH.w * xB1.w;
            }
            pre0 = a0 + bs;
            pre1 = a1 + bs;
        }

        if (actL1 || actL2) {
            float i0 = __shfl(pre0, sbase + 0, 64);
            float f0 = __shfl(pre0, sbase + 2, 64);
            float g0 = __shfl(pre0, sbase + 4, 64);
            float o0 = __shfl(pre0, sbase + 6, 64);
            float i1 = __shfl(pre1, sbase + 0, 64);
            float f1 = __shfl(pre1, sbase + 2, 64);
            float g1 = __shfl(pre1, sbase + 4, 64);
            float o1 = __shfl(pre1, sbase + 6, 64);

            if (r < 2) {
                float ia = sigmoidf_(i0), fa = sigmoidf_(f0);
                float ga = tanhf(g0),     oa = sigmoidf_(o0);
                c0 = fa * c0 + ia * ga;
                float h0 = oa * tanhf(c0);
                float ib = sigmoidf_(i1), fb = sigmoidf_(f1);
                float gb = tanhf(g1),     ob = sigmoidf_(o1);
                c1 = fb * c1 + ib * gb;
                float h1n = ob * tanhf(c1);
                // L1 publishes h1_i -> slot i&1; L2 publishes h2_{i-1} -> slot (i+1)&1
                float* dst = actL1 ? (h1r + (size_t)(i & 1) * BBHH)
                                   : (h2r + (size_t)((i + 1) & 1) * BBHH);
                dst[b0 * HH + u0 + r] = h0;
                dst[b1 * HH + u0 + r] = h1n;
            }
        }

        // device-wide barrier (padded lines, sleep backoff)
        __syncthreads();
        if (tid == 0) {
            __threadfence();
            ++phase;
            unsigned old = atomicAdd(&bar->count, 1u);
            if (old == (unsigned)NWGT * phase - 1u) {
                __hip_atomic_store(&bar->phase, phase, __ATOMIC_RELEASE,
                                   __HIP_MEMORY_SCOPE_AGENT);
            } else {
                while (__hip_atomic_load(&bar->phase, __ATOMIC_ACQUIRE,
                                         __HIP_MEMORY_SCOPE_AGENT) < phase)
                    __builtin_amdgcn_s_sleep(2);
            }
            __threadfence();
        } else {
            // nothing
        }
        __syncthreads();
    }

    if (r < 2) {
        cbuf[b0 * HH + u0 + r] = c0;
        cbuf[b1 * HH + u0 + r] = c1;
    }
}

// ---------------------------------------------------------------------------
__global__ void fc_kernel(const float* __restrict__ h2,
                          const float* __restrict__ Wfc,
                          const float* __restrict__ bfc,
                          float* __restrict__ out)
{
    __shared__ float hs[256];
    int b = blockIdx.x, tid = threadIdx.x;
    hs[tid] = h2[b * HH + tid];
    __syncthreads();
    if (tid < NC) {
        float s = bfc[tid];
        for (int k = 0; k < 256; k++) s += hs[k] * Wfc[tid * 256 + k];
        out[b * NC + tid] = s;
    }
}

// ---------------------------------------------------------------------------
extern "C" void kernel_launch(void* const* d_in, const int* in_sizes, int n_in,
                              void* d_out, int out_size, void* d_ws, size_t ws_size,
                              hipStream_t stream)
{
    const float* x    = (const float*)d_in[0];
    const float* Wih0 = (const float*)d_in[1];
    const float* Whh0 = (const float*)d_in[2];
    const float* bih0 = (const float*)d_in[3];
    const float* bhh0 = (const float*)d_in[4];
    const float* Wih1 = (const float*)d_in[5];
    const float* Whh1 = (const float*)d_in[6];
    const float* bih1 = (const float*)d_in[7];
    const float* bhh1 = (const float*)d_in[8];
    const float* Wfc  = (const float*)d_in[9];
    const float* bfc  = (const float*)d_in[10];

    float* ws = (float*)d_ws;

    int TC = TT;
    while (TC > 128) {
        size_t need = ((size_t)TC * BB * H4 + 6 * BBHH + 512) * 4;
        if (need <= ws_size) break;
        TC >>= 1;
    }

    float* gxb = ws;
    float* h1r = gxb + (size_t)TC * BB * H4;
    float* h2r = h1r + 2 * BBHH;
    float* c1b = h2r + 2 * BBHH;
    float* c2b = c1b + BBHH;
    uintptr_t bp = ((uintptr_t)(c2b + BBHH) + 255) & ~(uintptr_t)255;
    Bar* bar = (Bar*)bp;

    // zero rings + cell states once (contiguous 6*BBHH floats)
    hipMemsetAsync(h1r, 0, (size_t)6 * BBHH * 4, stream);

    const int nchunk = TT / TC;
    for (int ch = 0; ch < nchunk; ch++) {
        int t0 = ch * TC;
        dim3 gg(8, TC * 64 / 128);
        gemm_gx<<<gg, 256, 0, stream>>>(x, Wih0, bih0, bhh0, gxb, t0);
        hipMemsetAsync(bar, 0, sizeof(Bar), stream);
        int last = (ch == nchunk - 1) ? 1 : 0;
        lstm_rec2<<<NWGT, 256, 0, stream>>>(gxb, Whh0, Wih1, Whh1, bih1, bhh1,
                                            h1r, h2r, c1b, c2b, bar,
                                            t0, TC, TC + last);
    }

    // h2_{T-1} lives in slot (T-1)&1
    fc_kernel<<<BB, 256, 0, stream>>>(h2r + (size_t)((TT - 1) & 1) * BBHH,
                                      Wfc, bfc, (float*)d_out);
}